// Round 1
// baseline (930.967 us; speedup 1.0000x reference)
//
#include <hip/hip_runtime.h>

#define BS_N 1048576
#define NH 64
#define NK 64

// ws layout (floats): [0:512) colsum replicas (8 x 64), [512:576) c2[k]
#define WS_C2_OFF 512

__device__ __forceinline__ float frcp(float x) { return __builtin_amdgcn_rcpf(x); }

// K0: zero colsum replicas, precompute ||c_k||^2. One block, 128 threads.
__global__ void k0_init(const float* __restrict__ c, float* __restrict__ ws) {
    const int t = threadIdx.x;
    for (int i = t; i < 512; i += 128) ws[i] = 0.f;
    if (t < 64) {
        const float* row = c + t * NH;
        float s0 = 0.f, s1 = 0.f, s2 = 0.f, s3 = 0.f;
#pragma unroll
        for (int h = 0; h < NH; h += 4) {
            s0 = fmaf(row[h + 0], row[h + 0], s0);
            s1 = fmaf(row[h + 1], row[h + 1], s1);
            s2 = fmaf(row[h + 2], row[h + 2], s2);
            s3 = fmaf(row[h + 3], row[h + 3], s3);
        }
        ws[WS_C2_OFF + t] = (s0 + s1) + (s2 + s3);
    }
}

// K1 v2: one row per thread, zero LDS, qu[] kept in VGPRs.
//  - c loads are wave-uniform reads of a const __restrict__ never-written arg
//    -> hipcc scalarizes to s_load; fmacs then read c from SGPRs (free broadcast).
//  - c2 passed as its OWN restrict pointer (not via ws) so it can't alias the
//    colsum atomics -> stays scalarizable too.
//  - column sums via in-register 64-lane butterfly transpose-reduce:
//    after 6 stages lane l holds the wave's colsum for k=l; one atomic per wave.
__global__ __launch_bounds__(256) void k1_q(const float* __restrict__ z,
                                            const float* __restrict__ c,
                                            const float* __restrict__ c2p,
                                            float* __restrict__ colsum_base,
                                            float* __restrict__ Q) {
    const int t = threadIdx.x;
    const int lane = t & 63;
    const long long row = (long long)blockIdx.x * 256 + t;

    // z row -> 64 VGPRs (16B/lane streaming loads)
    const float4* __restrict__ z4 = reinterpret_cast<const float4*>(z) + row * 16;
    float zr[NH];
#pragma unroll
    for (int i = 0; i < 16; i++) {
        float4 v = z4[i];
        zr[4 * i + 0] = v.x; zr[4 * i + 1] = v.y;
        zr[4 * i + 2] = v.z; zr[4 * i + 3] = v.w;
    }
    float z20 = 0.f, z21 = 0.f, z22 = 0.f, z23 = 0.f;
#pragma unroll
    for (int h = 0; h < NH; h += 4) {
        z20 = fmaf(zr[h + 0], zr[h + 0], z20);
        z21 = fmaf(zr[h + 1], zr[h + 1], z21);
        z22 = fmaf(zr[h + 2], zr[h + 2], z22);
        z23 = fmaf(zr[h + 3], zr[h + 3], z23);
    }
    const float z2 = (z20 + z21) + (z22 + z23);

    // unnormalized Student-t kernel values, fully register-resident
    float qu[NK];
    const float4* __restrict__ c4 = reinterpret_cast<const float4*>(c);
#pragma unroll
    for (int k = 0; k < NK; k++) {
        float a0 = 0.f, a1 = 0.f, a2 = 0.f, a3 = 0.f;
#pragma unroll
        for (int i = 0; i < 16; i++) {
            const float4 cv = c4[k * 16 + i];  // uniform -> s_load, SGPR operand
            a0 = fmaf(zr[4 * i + 0], cv.x, a0);
            a1 = fmaf(zr[4 * i + 1], cv.y, a1);
            a2 = fmaf(zr[4 * i + 2], cv.z, a2);
            a3 = fmaf(zr[4 * i + 3], cv.w, a3);
        }
        const float dot = (a0 + a1) + (a2 + a3);
        float d2 = z2 + c2p[k] - 2.f * dot;
        d2 = fmaxf(d2, 0.f);
        const float sim = sqrtf(d2);
        qu[k] = frcp(1.f + sim);  // (1+sim/a)^(-(a+1)/2), a=1
    }

    // row sum (static-indexed tree, 4-way ILP)
    float rs0 = 0.f, rs1 = 0.f, rs2 = 0.f, rs3 = 0.f;
#pragma unroll
    for (int k = 0; k < NK; k += 4) {
        rs0 += qu[k + 0]; rs1 += qu[k + 1];
        rs2 += qu[k + 2]; rs3 += qu[k + 3];
    }
    const float rinv = frcp((rs0 + rs1) + (rs2 + rs3));

    // normalize in-register, write Q row (float4)
    float4* __restrict__ Q4 = reinterpret_cast<float4*>(Q) + row * 16;
#pragma unroll
    for (int i = 0; i < 16; i++) {
        float4 o;
        o.x = qu[4 * i + 0] * rinv;
        o.y = qu[4 * i + 1] * rinv;
        o.z = qu[4 * i + 2] * rinv;
        o.w = qu[4 * i + 3] * rinv;
        qu[4 * i + 0] = o.x; qu[4 * i + 1] = o.y;
        qu[4 * i + 2] = o.z; qu[4 * i + 3] = o.w;
        Q4[i] = o;
    }

    // Butterfly transpose-reduce across the wave: stage r keeps the k-half whose
    // bit r matches the lane's bit r, packed to qu[0..n). All indices static;
    // selects compile to v_cndmask. After 6 stages qu[0] = colsum for k = lane.
#pragma unroll
    for (int r = 0; r < 6; r++) {
        const int n = NK >> (r + 1);
        const bool hi = (lane >> r) & 1;
#pragma unroll
        for (int i = 0; i < n; i++) {
            const float mine = hi ? qu[2 * i + 1] : qu[2 * i];
            const float oth  = hi ? qu[2 * i]     : qu[2 * i + 1];
            qu[i] = mine + __shfl_xor(oth, 1 << r, 64);
        }
    }
    float* colsum = colsum_base + (size_t)(blockIdx.x & 7) * 64;
    atomicAdd(&colsum[lane], qu[0]);  // one 64-lane atomic per wave
}

// K2: P = rownorm(Q^2 / colsum). Reversed block order for L3 reuse of Q's tail.
__global__ __launch_bounds__(256) void k2_p(const float* __restrict__ ws,
                                            const float* __restrict__ Q,
                                            float* __restrict__ P) {
    __shared__ __align__(16) float rcs[64];
    const int t = threadIdx.x;
    if (t < 64) {
        float s = 0.f;
#pragma unroll
        for (int rep = 0; rep < 8; rep++) s += ws[rep * 64 + t];
        rcs[t] = frcp(s);
    }
    __syncthreads();

    const long long row = (long long)(gridDim.x - 1 - blockIdx.x) * 256 + t;
    const float4* Q4 = reinterpret_cast<const float4*>(Q) + row * 16;
    float4* P4 = reinterpret_cast<float4*>(P) + row * 16;

    float pu[NK];
    float s0 = 0.f, s1 = 0.f, s2 = 0.f, s3 = 0.f;
#pragma unroll
    for (int i = 0; i < 16; i++) {
        float4 v = Q4[i];
        float4 cc = *reinterpret_cast<const float4*>(&rcs[4 * i]);
        pu[4 * i + 0] = v.x * v.x * cc.x; s0 += pu[4 * i + 0];
        pu[4 * i + 1] = v.y * v.y * cc.y; s1 += pu[4 * i + 1];
        pu[4 * i + 2] = v.z * v.z * cc.z; s2 += pu[4 * i + 2];
        pu[4 * i + 3] = v.w * v.w * cc.w; s3 += pu[4 * i + 3];
    }
    const float rinv = frcp((s0 + s1) + (s2 + s3));
#pragma unroll
    for (int i = 0; i < 16; i++) {
        float4 o;
        o.x = pu[4 * i + 0] * rinv;
        o.y = pu[4 * i + 1] * rinv;
        o.z = pu[4 * i + 2] * rinv;
        o.w = pu[4 * i + 3] * rinv;
        P4[i] = o;
    }
}

extern "C" void kernel_launch(void* const* d_in, const int* in_sizes, int n_in,
                              void* d_out, int out_size, void* d_ws, size_t ws_size,
                              hipStream_t stream) {
    const float* z = (const float*)d_in[0];
    const float* c = (const float*)d_in[1];
    float* Q = (float*)d_out;
    float* P = (float*)d_out + (size_t)BS_N * NK;
    float* ws = (float*)d_ws;

    k0_init<<<1, 128, 0, stream>>>(c, ws);
    k1_q<<<BS_N / 256, 256, 0, stream>>>(z, c, ws + WS_C2_OFF, ws, Q);
    k2_p<<<BS_N / 256, 256, 0, stream>>>(ws, Q, P);
}